// Round 4
// baseline (222.552 us; speedup 1.0000x reference)
//
#include <hip/hip_runtime.h>

// Problem constants (from reference): B=64, S=4096, D=256, LABELS=50
#define BB  64
#define SS  4096
#define DD  256
#define LBL 50

// 32 contiguous rows (32 KB) per chunk -> 128 chunks/batch, 8192 blocks.
// ~2048 blocks resident; the rest dispatched ON-DEMAND as blocks retire ->
// the HW dispatcher is the load balancer (static grids pin chunk-index per
// CU -> 2x imbalance, measured round 0). Chunks stay contiguous (stride-256
// interleave killed locality, round 1).
#define CROWS  32
#define NCHUNK (SS / CROWS)      // 128

typedef float f4 __attribute__((ext_vector_type(4)));

static __device__ __forceinline__ f4 vmax4(f4 a, f4 b) {
    f4 r;
    r.x = fmaxf(a.x, b.x);
    r.y = fmaxf(a.y, b.y);
    r.z = fmaxf(a.z, b.z);
    r.w = fmaxf(a.w, b.w);
    return r;
}

// Order-preserving float->uint map: umax(map(a),map(b)) == map(fmaxf(a,b))
// for all finite floats (and infs). Bit-exact roundtrip. Every value maps
// > 0 (min is map(-inf)=0x007FFFFF), so a ZERO-initialized pool acts as the
// -inf identity -> plain memset suffices, no pattern fill.
static __device__ __forceinline__ unsigned fmap(float x) {
    unsigned b = __float_as_uint(x);
    return (b & 0x80000000u) ? ~b : (b | 0x80000000u);
}
static __device__ __forceinline__ float funmap(unsigned u) {
    unsigned b = (u & 0x80000000u) ? (u ^ 0x80000000u) : ~u;
    return __uint_as_float(b);
}

// Fused kernel: per-(batch, 32-row chunk) partial max -> device atomicMax
// into pool[b][d] -> last-arriving block of each batch runs the [256]x[256,50]
// GEMV. Per-batch finalize overlaps other batches' streaming; only the last
// batch's finalize (~1-2us) is exposed. No second dispatch, no partial
// round-trip.
__global__ __launch_bounds__(256) void fused_segmax_kernel(
    const float* __restrict__ code,      // [B, S, D]
    const int*   __restrict__ lengths,   // [B]
    const float* __restrict__ Wp,        // [LBL, D] row-major
    float*       __restrict__ out,       // [B, LBL]
    unsigned*    __restrict__ pool,      // [B * D]  (zeroed)
    unsigned*    __restrict__ done)      // [B]      (zeroed)
{
    int bid = blockIdx.x;
    int b   = bid >> 7;                  // bid / NCHUNK
    int c   = bid & (NCHUNK - 1);
    int len = lengths[b];
    int s0  = c * CROWS;
    if (s0 >= len) return;               // uniform per block: no barrier hazard
    int s1 = min(s0 + CROWS, len);

    int wave = threadIdx.x >> 6;
    int lane = threadIdx.x & 63;

    const f4* p = (const f4*)(code + (size_t)b * SS * DD)
                + (size_t)(s0 + wave) * (DD / 4) + lane;
    const float neg = -INFINITY;
    f4 m = (f4){neg, neg, neg, neg};

    if (s1 - s0 == CROWS) {
        // Full chunk: 8 rows/wave, all loads issued before reducing (MLP=8).
        f4 v0 = __builtin_nontemporal_load(p + 0 * 256);
        f4 v1 = __builtin_nontemporal_load(p + 1 * 256);
        f4 v2 = __builtin_nontemporal_load(p + 2 * 256);
        f4 v3 = __builtin_nontemporal_load(p + 3 * 256);
        f4 v4 = __builtin_nontemporal_load(p + 4 * 256);
        f4 v5 = __builtin_nontemporal_load(p + 5 * 256);
        f4 v6 = __builtin_nontemporal_load(p + 6 * 256);
        f4 v7 = __builtin_nontemporal_load(p + 7 * 256);
        m = vmax4(vmax4(vmax4(v0, v1), vmax4(v2, v3)),
                  vmax4(vmax4(v4, v5), vmax4(v6, v7)));
    } else {
        // Boundary chunk (len cuts inside): generic strided loop.
        for (int s = s0 + wave; s < s1; s += 4, p += 4 * (DD / 4))
            m = vmax4(m, __builtin_nontemporal_load(p));
    }

    __shared__ f4   red[4][64];
    __shared__ float poolf[DD];
    __shared__ int  is_last;
    red[wave][lane] = m;
    __syncthreads();

    if (threadIdx.x < 64) {
        f4 a = red[0][lane];
        #pragma unroll
        for (int w = 1; w < 4; ++w)
            a = vmax4(a, red[w][lane]);
        unsigned* dst = pool + b * DD + lane * 4;
        // Fire-and-forget device-scope atomics (no return value needed).
        __hip_atomic_fetch_max(dst + 0, fmap(a.x), __ATOMIC_RELAXED, __HIP_MEMORY_SCOPE_AGENT);
        __hip_atomic_fetch_max(dst + 1, fmap(a.y), __ATOMIC_RELAXED, __HIP_MEMORY_SCOPE_AGENT);
        __hip_atomic_fetch_max(dst + 2, fmap(a.z), __ATOMIC_RELAXED, __HIP_MEMORY_SCOPE_AGENT);
        __hip_atomic_fetch_max(dst + 3, fmap(a.w), __ATOMIC_RELAXED, __HIP_MEMORY_SCOPE_AGENT);
    }
    // __syncthreads drains vmcnt (barrier semantics: all memory ops complete
    // before any wave crosses) -> wave 0's pool atomics are performed before
    // the done[] increment below.
    __syncthreads();

    if (threadIdx.x == 0) {
        int nact = (len + CROWS - 1) / CROWS;      // active chunks for batch b
        if (nact > NCHUNK) nact = NCHUNK;
        unsigned old = __hip_atomic_fetch_add(&done[b], 1u,
                                              __ATOMIC_ACQ_REL, __HIP_MEMORY_SCOPE_AGENT);
        is_last = (old == (unsigned)(nact - 1));
    }
    __syncthreads();
    if (!is_last) return;

    // Finalize batch b: agent-scope atomic loads bypass stale local caches,
    // guaranteed to see all completed pool atomics.
    unsigned u = __hip_atomic_load(&pool[b * DD + threadIdx.x],
                                   __ATOMIC_RELAXED, __HIP_MEMORY_SCOPE_AGENT);
    poolf[threadIdx.x] = funmap(u);
    __syncthreads();

    if (threadIdx.x < LBL) {
        float acc = 0.0f;
        const float* w = Wp + (size_t)threadIdx.x * DD;
        #pragma unroll 8
        for (int d = 0; d < DD; ++d)
            acc += poolf[d] * w[d];      // poolf[d]: same addr all lanes -> LDS broadcast
        out[b * LBL + threadIdx.x] = acc;
    }
}

extern "C" void kernel_launch(void* const* d_in, const int* in_sizes, int n_in,
                              void* d_out, int out_size, void* d_ws, size_t ws_size,
                              hipStream_t stream) {
    // Input order (setup_inputs): 0 find_contri, 1 contri, 2 code_output,
    // 3 lengths, 4 hidden, 5 W_attn, 6 b_attn, 7 W_pool.
    // energy is dead compute in the reference -> hidden/W_attn/b_attn unused.
    const float* code    = (const float*)d_in[2];
    const int*   lengths = (const int*)  d_in[3];
    const float* Wp      = (const float*)d_in[7];
    float*       out     = (float*)d_out;

    unsigned* pool = (unsigned*)d_ws;            // [BB*DD]  64 KB
    unsigned* done = (unsigned*)d_ws + BB * DD;  // [BB]     256 B
    (void)ws_size;                               // need 66 KB of ~1 GB

    // Zero init: pool zeros are the -inf identity under the monotone map;
    // done counters start at 0. Memset nodes are graph-capturable.
    hipMemsetAsync(d_ws, 0, (size_t)(BB * DD + BB) * sizeof(unsigned), stream);

    fused_segmax_kernel<<<BB * NCHUNK, 256, 0, stream>>>(
        code, lengths, Wp, out, pool, done);
}

// Round 5
// 31.677 us; speedup vs baseline: 7.0257x; 7.0257x over previous
//
#include <hip/hip_runtime.h>

// Problem constants (from reference): B=64, S=4096, D=256, LABELS=50
#define BB  64
#define SS  4096
#define DD  256
#define LBL 50

// 64 contiguous rows (64 KB) per chunk, 512-thread blocks -> 4096 blocks,
// 1024 resident (4/CU) -> 4x oversubscribed: the HW on-demand dispatcher is
// the load balancer (static grids pin chunk-index per CU -> 2x imbalance,
// round 0). Chunks contiguous (stride interleave killed locality, round 1).
// CROWS 32->64 halves block count: ~50% of blocks are EMPTY (c >= len/CROWS,
// ~0.25us slot time each) and every block pays setup/retire overhead; round-4
// counters showed LLC serves ~half the stream, so the floor is well below
// 32us and these fixed costs are the residual theory.
// Atomic-pool fusion (round 4): catastrophic (agent-scope atomics serialize
// block retirement on non-coherent-L2 chiplets). Two dispatches it is.
#define CROWS  64
#define NCHUNK (SS / CROWS)      // 64 chunks/batch

typedef float f4 __attribute__((ext_vector_type(4)));

static __device__ __forceinline__ f4 vmax4(f4 a, f4 b) {
    f4 r;
    r.x = fmaxf(a.x, b.x);
    r.y = fmaxf(a.y, b.y);
    r.z = fmaxf(a.z, b.z);
    r.w = fmaxf(a.w, b.w);
    return r;
}

// Kernel 1: per-(batch, 64-row chunk) partial max over valid rows.
// Block = 512 threads = 8 waves; wave w rows s0+w, s0+w+8, ... (8 when full).
// Lane holds a float4 column slice -> one wave covers a full 1KB row/iter,
// fully coalesced; 8 loads in flight per wave before any reduction.
// code is read once -> nontemporal (no cache-allocate pollution).
__global__ __launch_bounds__(512) void segmax_partial_kernel(
    const float* __restrict__ code,      // [B, S, D]
    const int*   __restrict__ lengths,   // [B]
    float*       __restrict__ partial)   // [B * NCHUNK, D]
{
    int bid = blockIdx.x;
    int b   = bid >> 6;                  // bid / NCHUNK
    int c   = bid & (NCHUNK - 1);
    int len = lengths[b];
    int s0  = c * CROWS;
    if (s0 >= len) return;               // uniform per block: no barrier hazard
    int s1 = min(s0 + CROWS, len);

    int wave = threadIdx.x >> 6;         // 0..7
    int lane = threadIdx.x & 63;

    const f4* p = (const f4*)(code + (size_t)b * SS * DD)
                + (size_t)(s0 + wave) * (DD / 4) + lane;
    const float neg = -INFINITY;
    f4 m = (f4){neg, neg, neg, neg};

    if (s1 - s0 == CROWS) {
        // Full chunk: 8 rows/wave at stride 8 rows (512 f4), MLP=8.
        f4 v0 = __builtin_nontemporal_load(p + 0 * 512);
        f4 v1 = __builtin_nontemporal_load(p + 1 * 512);
        f4 v2 = __builtin_nontemporal_load(p + 2 * 512);
        f4 v3 = __builtin_nontemporal_load(p + 3 * 512);
        f4 v4 = __builtin_nontemporal_load(p + 4 * 512);
        f4 v5 = __builtin_nontemporal_load(p + 5 * 512);
        f4 v6 = __builtin_nontemporal_load(p + 6 * 512);
        f4 v7 = __builtin_nontemporal_load(p + 7 * 512);
        m = vmax4(vmax4(vmax4(v0, v1), vmax4(v2, v3)),
                  vmax4(vmax4(v4, v5), vmax4(v6, v7)));
    } else {
        // Boundary chunk (len cuts inside): generic strided loop.
        for (int s = s0 + wave; s < s1; s += 8, p += 8 * (DD / 4))
            m = vmax4(m, __builtin_nontemporal_load(p));
    }

    __shared__ f4 red[8][64];
    red[wave][lane] = m;
    __syncthreads();

    if (threadIdx.x < 64) {
        f4 a = red[0][lane];
        #pragma unroll
        for (int w = 1; w < 8; ++w)
            a = vmax4(a, red[w][lane]);
        f4* dst = (f4*)(partial + (size_t)bid * DD);
        dst[lane] = a;                   // normal store: re-read by finalize
    }
}

// Kernel 2: per-batch final reduce over active partials + [256]x[256,50] dot.
// 1024 threads = 16 waves (64-block grid lights only 64 CUs; per-CU MLP is
// the lever). nact <= 64 -> at most 4 strided loads per wave.
__global__ __launch_bounds__(1024) void finalize_kernel(
    const float* __restrict__ partial,   // [B * NCHUNK, D]
    const int*   __restrict__ lengths,   // [B]
    const float* __restrict__ Wp,        // [LBL, D] row-major
    float*       __restrict__ out)       // [B, LBL]
{
    int b    = blockIdx.x;
    int wave = threadIdx.x >> 6;         // 0..15
    int lane = threadIdx.x & 63;
    int len  = lengths[b];
    int nact = (len + CROWS - 1) / CROWS;          // chunks that wrote a partial
    if (nact > NCHUNK) nact = NCHUNK;

    const f4* pb = (const f4*)partial + (size_t)b * NCHUNK * (DD / 4) + lane;
    const float neg = -INFINITY;
    f4 m = (f4){neg, neg, neg, neg};

    int c = wave;
    for (; c + 48 < nact; c += 64) {               // full nact=64: one round, MLP=4
        f4 a0 = __builtin_nontemporal_load(pb + (size_t)(c     ) * (DD / 4));
        f4 a1 = __builtin_nontemporal_load(pb + (size_t)(c + 16) * (DD / 4));
        f4 a2 = __builtin_nontemporal_load(pb + (size_t)(c + 32) * (DD / 4));
        f4 a3 = __builtin_nontemporal_load(pb + (size_t)(c + 48) * (DD / 4));
        m = vmax4(m, vmax4(vmax4(a0, a1), vmax4(a2, a3)));
    }
    for (; c < nact; c += 16)
        m = vmax4(m, __builtin_nontemporal_load(pb + (size_t)c * (DD / 4)));

    __shared__ f4 red[16][64];
    __shared__ float pool[DD];
    red[wave][lane] = m;
    __syncthreads();

    if (threadIdx.x < 64) {
        f4 a = red[0][lane];
        #pragma unroll
        for (int w = 1; w < 16; ++w)
            a = vmax4(a, red[w][lane]);
        ((f4*)pool)[lane] = a;
    }
    __syncthreads();

    if (threadIdx.x < LBL) {
        float acc = 0.0f;
        const float* w = Wp + (size_t)threadIdx.x * DD;
        #pragma unroll 8
        for (int d = 0; d < DD; ++d)
            acc += pool[d] * w[d];       // pool[d]: same addr all lanes -> LDS broadcast
        out[b * LBL + threadIdx.x] = acc;
    }
}

extern "C" void kernel_launch(void* const* d_in, const int* in_sizes, int n_in,
                              void* d_out, int out_size, void* d_ws, size_t ws_size,
                              hipStream_t stream) {
    // Input order (setup_inputs): 0 find_contri, 1 contri, 2 code_output,
    // 3 lengths, 4 hidden, 5 W_attn, 6 b_attn, 7 W_pool.
    // energy is dead compute in the reference -> hidden/W_attn/b_attn unused.
    const float* code    = (const float*)d_in[2];
    const int*   lengths = (const int*)  d_in[3];
    const float* Wp      = (const float*)d_in[7];
    float*       out     = (float*)d_out;
    float*       partial = (float*)d_ws;

    // Workspace need: 64 * 64 * 256 * 4B = 4 MB (ws is ~1 GB).
    (void)ws_size;

    segmax_partial_kernel<<<BB * NCHUNK, 512, 0, stream>>>(code, lengths, partial);
    finalize_kernel<<<BB, 1024, 0, stream>>>(partial, lengths, Wp, out);
}